// Round 6
// baseline (20940.804 us; speedup 1.0000x reference)
//
#include <hip/hip_runtime.h>
#include <cmath>

#define BATCHN 256
#define SEQT   1024
#define EMBED  1024
#define HID    1024
#define VOCABN 32000

typedef __attribute__((ext_vector_type(8))) _Float16 half8;
typedef __attribute__((ext_vector_type(4))) _Float16 half4;
typedef __attribute__((ext_vector_type(4))) float    float4v;
typedef __attribute__((ext_vector_type(4))) unsigned int uint4v;

#define LOSCALE 4096.0f
#define LOINV   (1.0f/4096.0f)

union FU16 { _Float16 f; unsigned short u; };
__device__ inline unsigned short f16bits(_Float16 f){ FU16 t; t.f=f; return t.u; }
__device__ inline _Float16 bits16(unsigned short u){ FU16 t; t.u=u; return t.f; }

__device__ inline void async16(const void* g, void* l) {
  __builtin_amdgcn_global_load_lds(
      (const __attribute__((address_space(1))) void*)g,
      (__attribute__((address_space(3))) void*)l, 16, 0, 0);
}

// ---------------- f32 -> f16 convert ----------------
__global__ void convert_f32_f16(const float* __restrict__ in,
                                _Float16* __restrict__ out, int n) {
  int i = (blockIdx.x * blockDim.x + threadIdx.x) * 4;
  if (i + 3 < n) {
    float4v v = *reinterpret_cast<const float4v*>(in + i);
    half4 o;
#pragma unroll
    for (int j = 0; j < 4; ++j) o[j] = (_Float16)v[j];
    *reinterpret_cast<half4*>(out + i) = o;
  }
}

// ---------------- f32 -> f16 hi/lo split (lo pre-scaled by 2^12) ----------------
__global__ void split_f32_f16(const float* __restrict__ in,
                              _Float16* __restrict__ hi,
                              _Float16* __restrict__ lo, int n) {
  int i = (blockIdx.x * blockDim.x + threadIdx.x) * 4;
  if (i + 3 < n) {
    float4v v = *reinterpret_cast<const float4v*>(in + i);
    half4 h, l;
#pragma unroll
    for (int j = 0; j < 4; ++j) {
      h[j] = (_Float16)v[j];
      l[j] = (_Float16)((v[j] - (float)h[j]) * LOSCALE);
    }
    *reinterpret_cast<half4*>(hi + i) = h;
    *reinterpret_cast<half4*>(lo + i) = l;
  }
}

// ---------------- Phase 1: xi = emb[x] @ Wi^T + bi  (f16 MFMA, 128x128 tile) ----------------
// xi layout: m = tt*256 + b (t-major within chunk), n inner.
__global__ __launch_bounds__(256, 2) void gemm_xi(
    const _Float16* __restrict__ embh,  // [VOCAB][1024] f16
    const _Float16* __restrict__ Wih,   // [1024][1024] f16 (n-major, k inner)
    const int* __restrict__ x,          // [256][1024]
    const float* __restrict__ bi,       // [1024]
    _Float16* __restrict__ xi,          // [Tc*256][1024] f16
    int t0, int Tc)
{
  __shared__ __align__(16) _Float16 As[128 * 64];
  __shared__ __align__(16) _Float16 Bs[128 * 64];
  __shared__ __align__(16) _Float16 stage[128 * 132];
  __shared__ int toks[128];

  const int tid  = threadIdx.x;
  const int wid  = tid >> 6, lane = tid & 63;
  const int nt   = blockIdx.x & 7, mt = blockIdx.x >> 3;
  const int m0   = mt * 128, n0 = nt * 128;

  if (tid < 128) {
    int m  = m0 + tid;
    int tl = m >> 8;           // local t within chunk
    int b  = m & 255;          // batch row
    toks[tid] = x[b * SEQT + t0 + tl];
  }
  __syncthreads();

  const _Float16* aptr[4];
  const _Float16* bptr[4];
  int ldsoff[4];
#pragma unroll
  for (int i = 0; i < 4; ++i) {
    int idx = i * 256 + tid;
    int row = idx >> 3, kc = idx & 7;
    aptr[i]   = embh + (size_t)toks[row] * 1024 + kc * 8;
    bptr[i]   = Wih + ((size_t)(n0 + row) << 10) + kc * 8;
    ldsoff[i] = idx * 8;  // elements
  }

  float4v acc[4][4] = {};
  const int wm = wid & 1, wn = wid >> 1;
  const int cn = lane & 15, kg = lane >> 4;

  for (int k0 = 0; k0 < 1024; k0 += 64) {
#pragma unroll
    for (int i = 0; i < 4; ++i) {
      async16(aptr[i] + k0, &As[ldsoff[i]]);
      async16(bptr[i] + k0, &Bs[ldsoff[i]]);
    }
    __syncthreads();

    half8 a[4][2], b[4][2];
#pragma unroll
    for (int mf = 0; mf < 4; ++mf)
#pragma unroll
      for (int kf = 0; kf < 2; ++kf)
        a[mf][kf] = *reinterpret_cast<const half8*>(
            &As[(wm * 64 + mf * 16 + cn) * 64 + kf * 32 + kg * 8]);
#pragma unroll
    for (int nf = 0; nf < 4; ++nf)
#pragma unroll
      for (int kf = 0; kf < 2; ++kf)
        b[nf][kf] = *reinterpret_cast<const half8*>(
            &Bs[(wn * 64 + nf * 16 + cn) * 64 + kf * 32 + kg * 8]);

#pragma unroll
    for (int mf = 0; mf < 4; ++mf)
#pragma unroll
      for (int nf = 0; nf < 4; ++nf)
#pragma unroll
        for (int kf = 0; kf < 2; ++kf)
          acc[mf][nf] = __builtin_amdgcn_mfma_f32_16x16x32_f16(
              a[mf][kf], b[nf][kf], acc[mf][nf], 0, 0, 0);
    __syncthreads();
  }

  // epilogue: add bi, stage in LDS, coalesced 16B stores
#pragma unroll
  for (int nf = 0; nf < 4; ++nf) {
    int n = wn * 64 + nf * 16 + cn;
    float biv = bi[n0 + n];
#pragma unroll
    for (int mf = 0; mf < 4; ++mf) {
#pragma unroll
      for (int j = 0; j < 4; ++j) {
        int m = wm * 64 + mf * 16 + kg * 4 + j;
        stage[m * 132 + n] = (_Float16)(acc[mf][nf][j] + biv);
      }
    }
  }
  __syncthreads();
#pragma unroll
  for (int p = 0; p < 8; ++p) {
    int chunk = p * 256 + tid;
    int r = chunk >> 4, cc = chunk & 15;
    half4 v0 = *reinterpret_cast<const half4*>(stage + r * 132 + cc * 8);
    half4 v1 = *reinterpret_cast<const half4*>(stage + r * 132 + cc * 8 + 4);
    half8 o;
#pragma unroll
    for (int e = 0; e < 4; ++e) { o[e] = v0[e]; o[4 + e] = v1[e]; }
    *reinterpret_cast<half8*>(xi + ((size_t)(m0 + r) << 10) + n0 + cc * 8) = o;
  }
}

// ---------------- Phase 2: persistent scan, 256 WGs = 16 batch-groups x 16 col-groups ----
// Changes vs round 5: (1) weights pinned into AGPRs ("a" constraint) so the RA
// cannot spill/remat them through HBM each step; (2) contention-free flag
// barrier (one padded flag line per WG, monotone values, parallel polling);
// (3) xi prefetch for t+1 hoisted ahead of the barrier.
__global__ __launch_bounds__(256, 1) void rnn_scan(
    const _Float16* __restrict__ Whig,  // [1024][1024] f16 (n-major)
    const _Float16* __restrict__ Wlog,  // [1024][1024] f16 residual * 2^12
    const float* __restrict__ bh,       // [1024]
    const _Float16* __restrict__ xi,    // [Tc*256][1024] f16 (t-major)
    float* __restrict__ hstate,         // [256][1024] f32
    float* __restrict__ out,            // [256][1024] f32
    unsigned int* __restrict__ hexA,    // [256][1024] u32 packed hi|lo<<16
    unsigned int* __restrict__ hexB,
    int* __restrict__ bar,              // [16 groups][16 WGs][32 ints] flag lines (128B each)
    int t0, int Tc)
{
  __shared__ __align__(16) _Float16 Ahi[16 * 1024];
  __shared__ __align__(16) _Float16 Alo[16 * 1024];

  const int tid  = threadIdx.x;
  const int wv   = tid >> 6, lane = tid & 63;
  const int cn   = lane & 15, kg = lane >> 4;
  const int gb   = blockIdx.x >> 4;     // batch group (16 rows)
  const int gc   = blockIdx.x & 15;     // col group (64 cols)
  const int r0   = gb * 16;
  const int wcol = gc * 64 + wv * 16 + cn;  // this lane's output column

  // ---- Wh resident in AGPRs: 32 half8 hi + 32 half8 lo (256 AGPRs) ----
  half8 whi[32], wlo[32];
  {
    const _Float16* wp = Whig + ((size_t)wcol << 10) + kg * 8;
    const _Float16* lp = Wlog + ((size_t)wcol << 10) + kg * 8;
#pragma unroll
    for (int kk = 0; kk < 32; ++kk) {
      whi[kk] = *reinterpret_cast<const half8*>(wp + kk * 32);
      wlo[kk] = *reinterpret_cast<const half8*>(lp + kk * 32);
    }
  }
  // Pin into the AGPR bank: moves the 256-reg live range out of the arch-VGPR
  // pressure pool (round-5 showed "+v" pins just get spilled to scratch).
#pragma unroll
  for (int kk = 0; kk < 32; kk += 8) {
    asm volatile("" : "+a"(whi[kk]), "+a"(whi[kk+1]), "+a"(whi[kk+2]), "+a"(whi[kk+3]),
                      "+a"(whi[kk+4]), "+a"(whi[kk+5]), "+a"(whi[kk+6]), "+a"(whi[kk+7]));
    asm volatile("" : "+a"(wlo[kk]), "+a"(wlo[kk+1]), "+a"(wlo[kk+2]), "+a"(wlo[kk+3]),
                      "+a"(wlo[kk+4]), "+a"(wlo[kk+5]), "+a"(wlo[kk+6]), "+a"(wlo[kk+7]));
  }
  const float bhv = bh[wcol];

  // ---- init LDS h-tile (swizzle: byte ^= (row&7)<<4) ----
  if (t0 == 0) {
#pragma unroll
    for (int p = 0; p < 8; ++p) {
      int idx = p * 256 + tid, row = idx >> 7, cc = idx & 127;
      int bo = (((row << 11) + cc * 16) ^ ((row & 7) << 4));
      half8 z = {0, 0, 0, 0, 0, 0, 0, 0};
      *reinterpret_cast<half8*>(reinterpret_cast<char*>(Ahi) + bo) = z;
      *reinterpret_cast<half8*>(reinterpret_cast<char*>(Alo) + bo) = z;
    }
  } else {
#pragma unroll
    for (int p = 0; p < 8; ++p) {
      int idx = p * 256 + tid, row = idx >> 7, cc = idx & 127;
      const float* hp = hstate + (((size_t)(r0 + row)) << 10) + cc * 8;
      half8 vh, vl;
#pragma unroll
      for (int e = 0; e < 8; ++e) {
        float f = hp[e];
        _Float16 hi = (_Float16)f;
        vh[e] = hi;
        vl[e] = (_Float16)((f - (float)hi) * LOSCALE);
      }
      int bo = (((row << 11) + cc * 16) ^ ((row & 7) << 4));
      *reinterpret_cast<half8*>(reinterpret_cast<char*>(Ahi) + bo) = vh;
      *reinterpret_cast<half8*>(reinterpret_cast<char*>(Alo) + bo) = vl;
    }
  }
  __syncthreads();

  // xi prefetch for step 0
  unsigned short xiu[4];
#pragma unroll
  for (int j = 0; j < 4; ++j)
    xiu[j] = *reinterpret_cast<const unsigned short*>(
        xi + (((size_t)(r0 + kg * 4 + j)) << 10) + wcol);

  for (int tt = 0; tt < Tc; ++tt) {
    // per-step AGPR liveness pin (emits nothing; keeps RA from spilling)
#pragma unroll
    for (int kk = 0; kk < 32; kk += 8) {
      asm volatile("" :: "a"(whi[kk]), "a"(whi[kk+1]), "a"(whi[kk+2]), "a"(whi[kk+3]),
                         "a"(whi[kk+4]), "a"(whi[kk+5]), "a"(whi[kk+6]), "a"(whi[kk+7]));
      asm volatile("" :: "a"(wlo[kk]), "a"(wlo[kk+1]), "a"(wlo[kk+2]), "a"(wlo[kk+3]),
                         "a"(wlo[kk+4]), "a"(wlo[kk+5]), "a"(wlo[kk+6]), "a"(wlo[kk+7]));
    }

    // ---- 3-pass compensated matvec, 6 interleaved accumulators ----
    float4v a1a = {}, a1b = {}, a2a = {}, a2b = {}, a3a = {}, a3b = {};
#pragma unroll
    for (int kk = 0; kk < 32; ++kk) {
      int ab = (((cn << 11) + kk * 64 + kg * 16) ^ ((cn & 7) << 4));
      half8 ah = *reinterpret_cast<const half8*>(reinterpret_cast<const char*>(Ahi) + ab);
      half8 al = *reinterpret_cast<const half8*>(reinterpret_cast<const char*>(Alo) + ab);
      if (kk & 1) {
        a1b = __builtin_amdgcn_mfma_f32_16x16x32_f16(ah, whi[kk], a1b, 0, 0, 0);
        a2b = __builtin_amdgcn_mfma_f32_16x16x32_f16(al, whi[kk], a2b, 0, 0, 0);
        a3b = __builtin_amdgcn_mfma_f32_16x16x32_f16(ah, wlo[kk], a3b, 0, 0, 0);
      } else {
        a1a = __builtin_amdgcn_mfma_f32_16x16x32_f16(ah, whi[kk], a1a, 0, 0, 0);
        a2a = __builtin_amdgcn_mfma_f32_16x16x32_f16(al, whi[kk], a2a, 0, 0, 0);
        a3a = __builtin_amdgcn_mfma_f32_16x16x32_f16(ah, wlo[kk], a3a, 0, 0, 0);
      }
    }

    // ---- epilogue ----
    const int tglob = t0 + tt;
    unsigned int* hexW = ((tt + 1) & 1) ? hexA : hexB;
#pragma unroll
    for (int j = 0; j < 4; ++j) {
      int row = r0 + kg * 4 + j;
      float v = (a1a[j] + a1b[j]) +
                (a2a[j] + a2b[j] + a3a[j] + a3b[j]) * LOINV +
                bhv + (float)bits16(xiu[j]);
      float h = tanhf(v);
      if (tt < Tc - 1) {
        _Float16 hi = (_Float16)h;
        _Float16 lo = (_Float16)((h - (float)hi) * LOSCALE);
        unsigned int u = (unsigned int)f16bits(hi) | ((unsigned int)f16bits(lo) << 16);
        __hip_atomic_store(hexW + (((size_t)row) << 10) + wcol, u,
                           __ATOMIC_RELAXED, __HIP_MEMORY_SCOPE_AGENT);
      }
      if (tglob == SEQT - 1) out[(((size_t)row) << 10) + wcol] = h;
      else if (tt == Tc - 1) hstate[(((size_t)row) << 10) + wcol] = h;
    }
    if (tt == Tc - 1) break;  // no barrier/exchange after final step of chunk

    // xi prefetch for step tt+1 (issued before the barrier; hides HBM latency)
#pragma unroll
    for (int j = 0; j < 4; ++j)
      xiu[j] = *reinterpret_cast<const unsigned short*>(
          xi + (((size_t)((tt + 1) * 256 + r0 + kg * 4 + j)) << 10) + wcol);

    // ---- flag barrier: one padded line per WG, monotone values, no RMW ----
    __syncthreads();   // drains all waves' h stores (vmcnt 0 before s_barrier)
    if (tid == 0)
      __hip_atomic_store(bar + (gb * 16 + gc) * 32, tt + 1,
                         __ATOMIC_RELEASE, __HIP_MEMORY_SCOPE_AGENT);
    if (tid < 16) {
      const int* fp = bar + (gb * 16 + tid) * 32;
      while (__hip_atomic_load(fp, __ATOMIC_ACQUIRE, __HIP_MEMORY_SCOPE_AGENT) <= tt)
        __builtin_amdgcn_s_sleep(1);
    }
    __syncthreads();

    // ---- exchange: coherent-load full 16x1024 h, unpack to LDS ----
    const unsigned int* src = ((tt + 1) & 1) ? hexA : hexB;
    uint4v ta[8], tb[8];
#pragma unroll
    for (int p = 0; p < 8; ++p) {
      int idx = p * 256 + tid, row = idx >> 7, cc = idx & 127;
      unsigned long long ap =
          (unsigned long long)(src + (((size_t)(r0 + row)) << 10) + cc * 8);
      asm volatile("global_load_dwordx4 %0, %1, off sc0 sc1"
                   : "=v"(ta[p]) : "v"(ap) : "memory");
      asm volatile("global_load_dwordx4 %0, %1, off sc0 sc1"
                   : "=v"(tb[p]) : "v"(ap + 16) : "memory");
    }
    asm volatile("s_waitcnt vmcnt(0)" ::: "memory");
    __builtin_amdgcn_sched_barrier(0);
#pragma unroll
    for (int p = 0; p < 8; ++p) {
      int idx = p * 256 + tid, row = idx >> 7, cc = idx & 127;
      half8 vh, vl;
#pragma unroll
      for (int e = 0; e < 8; ++e) {
        unsigned int u = (e < 4) ? ta[p][e] : tb[p][e - 4];
        vh[e] = bits16((unsigned short)(u & 0xffffu));
        vl[e] = bits16((unsigned short)(u >> 16));
      }
      int bo = (((row << 11) + cc * 16) ^ ((row & 7) << 4));
      *reinterpret_cast<half8*>(reinterpret_cast<char*>(Ahi) + bo) = vh;
      *reinterpret_cast<half8*>(reinterpret_cast<char*>(Alo) + bo) = vl;
    }
    __syncthreads();
  }
}

extern "C" void kernel_launch(void* const* d_in, const int* in_sizes, int n_in,
                              void* d_out, int out_size, void* d_ws, size_t ws_size,
                              hipStream_t stream) {
  const int*   x   = (const int*)  d_in[0];
  const float* emb = (const float*)d_in[1];
  const float* Wi  = (const float*)d_in[2];
  const float* bi  = (const float*)d_in[3];
  const float* Wh  = (const float*)d_in[4];
  const float* bh  = (const float*)d_in[5];
  float* out = (float*)d_out;

  char* ws = (char*)d_ws;
  size_t off = 0;
  auto alloc = [&](size_t bytes) -> void* {
    void* p = ws + off;
    off = (off + bytes + 255) & ~(size_t)255;
    return p;
  };

  _Float16* embh   = (_Float16*)alloc((size_t)VOCABN * EMBED * 2);
  _Float16* Wih    = (_Float16*)alloc((size_t)HID * EMBED * 2);
  _Float16* Whih   = (_Float16*)alloc((size_t)HID * HID * 2);
  _Float16* Wloh   = (_Float16*)alloc((size_t)HID * HID * 2);
  float*    hstate = (float*)   alloc((size_t)BATCHN * HID * 4);
  unsigned int* hexA = (unsigned int*)alloc((size_t)BATCHN * HID * 4);
  unsigned int* hexB = (unsigned int*)alloc((size_t)BATCHN * HID * 4);
  int* bar  = (int*)alloc(16 * 16 * 32 * 4);   // 128B flag line per WG
  size_t fixed = off;

  // largest power-of-two T-chunk whose xi buffer fits in remaining ws
  int Tc = 1024;
  while (Tc > 4 && fixed + (size_t)BATCHN * Tc * HID * 2 > ws_size) Tc >>= 1;
  _Float16* xih = (_Float16*)alloc((size_t)BATCHN * Tc * HID * 2);

  {
    int n = VOCABN * EMBED;
    convert_f32_f16<<<n / 1024, 256, 0, stream>>>(emb, embh, n);
    n = HID * EMBED;
    convert_f32_f16<<<n / 1024, 256, 0, stream>>>(Wi, Wih, n);
    n = HID * HID;
    split_f32_f16<<<n / 1024, 256, 0, stream>>>(Wh, Whih, Wloh, n);
  }

  for (int t0 = 0; t0 < SEQT; t0 += Tc) {
    int grid = (BATCHN * Tc / 128) * 8;  // 128x128 tiles over [256*Tc, 1024]
    gemm_xi<<<grid, 256, 0, stream>>>(embh, Wih, x, bi, xih, t0, Tc);
    hipMemsetAsync(bar, 0, 16 * 16 * 32 * 4, stream);
    rnn_scan<<<256, 256, 0, stream>>>(Whih, Wloh, bh, xih, hstate, out,
                                      hexA, hexB, bar, t0, Tc);
  }
}

// Round 8
// 7311.967 us; speedup vs baseline: 2.8639x; 2.8639x over previous
//
#include <hip/hip_runtime.h>
#include <cmath>

#define BATCHN 256
#define SEQT   1024
#define EMBED  1024
#define HID    1024
#define VOCABN 32000

typedef __attribute__((ext_vector_type(8))) _Float16 half8;
typedef __attribute__((ext_vector_type(4))) _Float16 half4;
typedef __attribute__((ext_vector_type(4))) float    float4v;
typedef __attribute__((ext_vector_type(4))) unsigned int uint4v;

#define LOSCALE 4096.0f
#define LOINV   (1.0f/4096.0f)

union FU16 { _Float16 f; unsigned short u; };
__device__ inline unsigned short f16bits(_Float16 f){ FU16 t; t.f=f; return t.u; }
__device__ inline _Float16 bits16(unsigned short u){ FU16 t; t.u=u; return t.f; }

__device__ inline void async16(const void* g, void* l) {
  __builtin_amdgcn_global_load_lds(
      (const __attribute__((address_space(1))) void*)g,
      (__attribute__((address_space(3))) void*)l, 16, 0, 0);
}

// ---------------- f32 -> f16 convert ----------------
__global__ void convert_f32_f16(const float* __restrict__ in,
                                _Float16* __restrict__ out, int n) {
  int i = (blockIdx.x * blockDim.x + threadIdx.x) * 4;
  if (i + 3 < n) {
    float4v v = *reinterpret_cast<const float4v*>(in + i);
    half4 o;
#pragma unroll
    for (int j = 0; j < 4; ++j) o[j] = (_Float16)v[j];
    *reinterpret_cast<half4*>(out + i) = o;
  }
}

// ---------------- f32 -> f16 hi/lo split (lo pre-scaled by 2^12) ----------------
__global__ void split_f32_f16(const float* __restrict__ in,
                              _Float16* __restrict__ hi,
                              _Float16* __restrict__ lo, int n) {
  int i = (blockIdx.x * blockDim.x + threadIdx.x) * 4;
  if (i + 3 < n) {
    float4v v = *reinterpret_cast<const float4v*>(in + i);
    half4 h, l;
#pragma unroll
    for (int j = 0; j < 4; ++j) {
      h[j] = (_Float16)v[j];
      l[j] = (_Float16)((v[j] - (float)h[j]) * LOSCALE);
    }
    *reinterpret_cast<half4*>(hi + i) = h;
    *reinterpret_cast<half4*>(lo + i) = l;
  }
}

// ---------------- Phase 1: xi = emb[x] @ Wi^T + bi  (f16 MFMA, 128x128 tile) ----------------
// xi layout: m = tt*256 + b (t-major within chunk), n inner.
__global__ __launch_bounds__(256, 2) void gemm_xi(
    const _Float16* __restrict__ embh,  // [VOCAB][1024] f16
    const _Float16* __restrict__ Wih,   // [1024][1024] f16 (n-major, k inner)
    const int* __restrict__ x,          // [256][1024]
    const float* __restrict__ bi,       // [1024]
    _Float16* __restrict__ xi,          // [Tc*256][1024] f16
    int t0, int Tc)
{
  __shared__ __align__(16) _Float16 As[128 * 64];
  __shared__ __align__(16) _Float16 Bs[128 * 64];
  __shared__ __align__(16) _Float16 stage[128 * 132];
  __shared__ int toks[128];

  const int tid  = threadIdx.x;
  const int wid  = tid >> 6, lane = tid & 63;
  const int nt   = blockIdx.x & 7, mt = blockIdx.x >> 3;
  const int m0   = mt * 128, n0 = nt * 128;

  if (tid < 128) {
    int m  = m0 + tid;
    int tl = m >> 8;           // local t within chunk
    int b  = m & 255;          // batch row
    toks[tid] = x[b * SEQT + t0 + tl];
  }
  __syncthreads();

  const _Float16* aptr[4];
  const _Float16* bptr[4];
  int ldsoff[4];
#pragma unroll
  for (int i = 0; i < 4; ++i) {
    int idx = i * 256 + tid;
    int row = idx >> 3, kc = idx & 7;
    aptr[i]   = embh + (size_t)toks[row] * 1024 + kc * 8;
    bptr[i]   = Wih + ((size_t)(n0 + row) << 10) + kc * 8;
    ldsoff[i] = idx * 8;  // elements
  }

  float4v acc[4][4] = {};
  const int wm = wid & 1, wn = wid >> 1;
  const int cn = lane & 15, kg = lane >> 4;

  for (int k0 = 0; k0 < 1024; k0 += 64) {
#pragma unroll
    for (int i = 0; i < 4; ++i) {
      async16(aptr[i] + k0, &As[ldsoff[i]]);
      async16(bptr[i] + k0, &Bs[ldsoff[i]]);
    }
    __syncthreads();

    half8 a[4][2], b[4][2];
#pragma unroll
    for (int mf = 0; mf < 4; ++mf)
#pragma unroll
      for (int kf = 0; kf < 2; ++kf)
        a[mf][kf] = *reinterpret_cast<const half8*>(
            &As[(wm * 64 + mf * 16 + cn) * 64 + kf * 32 + kg * 8]);
#pragma unroll
    for (int nf = 0; nf < 4; ++nf)
#pragma unroll
      for (int kf = 0; kf < 2; ++kf)
        b[nf][kf] = *reinterpret_cast<const half8*>(
            &Bs[(wn * 64 + nf * 16 + cn) * 64 + kf * 32 + kg * 8]);

#pragma unroll
    for (int mf = 0; mf < 4; ++mf)
#pragma unroll
      for (int nf = 0; nf < 4; ++nf)
#pragma unroll
        for (int kf = 0; kf < 2; ++kf)
          acc[mf][nf] = __builtin_amdgcn_mfma_f32_16x16x32_f16(
              a[mf][kf], b[nf][kf], acc[mf][nf], 0, 0, 0);
    __syncthreads();
  }

  // epilogue: add bi, stage in LDS, coalesced 16B stores
#pragma unroll
  for (int nf = 0; nf < 4; ++nf) {
    int n = wn * 64 + nf * 16 + cn;
    float biv = bi[n0 + n];
#pragma unroll
    for (int mf = 0; mf < 4; ++mf) {
#pragma unroll
      for (int j = 0; j < 4; ++j) {
        int m = wm * 64 + mf * 16 + kg * 4 + j;
        stage[m * 132 + n] = (_Float16)(acc[mf][nf][j] + biv);
      }
    }
  }
  __syncthreads();
#pragma unroll
  for (int p = 0; p < 8; ++p) {
    int chunk = p * 256 + tid;
    int r = chunk >> 4, cc = chunk & 15;
    half4 v0 = *reinterpret_cast<const half4*>(stage + r * 132 + cc * 8);
    half4 v1 = *reinterpret_cast<const half4*>(stage + r * 132 + cc * 8 + 4);
    half8 o;
#pragma unroll
    for (int e = 0; e < 4; ++e) { o[e] = v0[e]; o[4 + e] = v1[e]; }
    *reinterpret_cast<half8*>(xi + ((size_t)(m0 + r) << 10) + n0 + cc * 8) = o;
  }
}

// ---------------- Phase 2: persistent scan, 256 WGs = 16 batch-groups x 16 col-groups ----
// Round-5 structure, but the per-step protocol is FENCE-FREE: all cross-WG ops are
// explicit sc0 sc1 (device-coherent, no buffer_inv/buffer_wbl2 cache maintenance),
// ordered by explicit s_waitcnt vmcnt(0) + __syncthreads. This keeps the Wh slices
// resident in each XCD's L2 (acquire fences were invalidating them every poll).
__global__ __launch_bounds__(256, 1) void rnn_scan(
    const _Float16* __restrict__ Whig,  // [1024][1024] f16 (n-major)
    const _Float16* __restrict__ Wlog,  // [1024][1024] f16 residual * 2^12
    const float* __restrict__ bh,       // [1024]
    const _Float16* __restrict__ xi,    // [Tc*256][1024] f16 (t-major)
    float* __restrict__ hstate,         // [256][1024] f32
    float* __restrict__ out,            // [256][1024] f32
    unsigned int* __restrict__ hexA,    // [256][1024] u32 packed hi|lo<<16
    unsigned int* __restrict__ hexB,
    int* __restrict__ bar,              // [256 WGs][32 ints] flag lines (128B each)
    int t0, int Tc)
{
  __shared__ __align__(16) _Float16 Ahi[16 * 1024];
  __shared__ __align__(16) _Float16 Alo[16 * 1024];

  const int tid  = threadIdx.x;
  const int wv   = tid >> 6, lane = tid & 63;
  const int cn   = lane & 15, kg = lane >> 4;
  const int gb   = blockIdx.x >> 4;     // batch group (16 rows)
  const int gc   = blockIdx.x & 15;     // col group (64 cols)
  const int r0   = gb * 16;
  const int wcol = gc * 64 + wv * 16 + cn;  // this lane's output column

  // ---- Wh slice (compiler streams from L2 each step; 208-VGPR regime) ----
  half8 whi[32], wlo[32];
  {
    const _Float16* wp = Whig + ((size_t)wcol << 10) + kg * 8;
    const _Float16* lp = Wlog + ((size_t)wcol << 10) + kg * 8;
#pragma unroll
    for (int kk = 0; kk < 32; ++kk) {
      whi[kk] = *reinterpret_cast<const half8*>(wp + kk * 32);
      wlo[kk] = *reinterpret_cast<const half8*>(lp + kk * 32);
    }
  }
  const float bhv = bh[wcol];

  // ---- init LDS h-tile (swizzle: byte ^= (row&7)<<4) ----
  if (t0 == 0) {
#pragma unroll
    for (int p = 0; p < 8; ++p) {
      int idx = p * 256 + tid, row = idx >> 7, cc = idx & 127;
      int bo = (((row << 11) + cc * 16) ^ ((row & 7) << 4));
      half8 z = {0, 0, 0, 0, 0, 0, 0, 0};
      *reinterpret_cast<half8*>(reinterpret_cast<char*>(Ahi) + bo) = z;
      *reinterpret_cast<half8*>(reinterpret_cast<char*>(Alo) + bo) = z;
    }
  } else {
#pragma unroll
    for (int p = 0; p < 8; ++p) {
      int idx = p * 256 + tid, row = idx >> 7, cc = idx & 127;
      const float* hp = hstate + (((size_t)(r0 + row)) << 10) + cc * 8;
      half8 vh, vl;
#pragma unroll
      for (int e = 0; e < 8; ++e) {
        float f = hp[e];
        _Float16 hi = (_Float16)f;
        vh[e] = hi;
        vl[e] = (_Float16)((f - (float)hi) * LOSCALE);
      }
      int bo = (((row << 11) + cc * 16) ^ ((row & 7) << 4));
      *reinterpret_cast<half8*>(reinterpret_cast<char*>(Ahi) + bo) = vh;
      *reinterpret_cast<half8*>(reinterpret_cast<char*>(Alo) + bo) = vl;
    }
  }
  __syncthreads();

  // xi prefetch for step 0
  unsigned short xiu[4];
#pragma unroll
  for (int j = 0; j < 4; ++j)
    xiu[j] = *reinterpret_cast<const unsigned short*>(
        xi + (((size_t)(r0 + kg * 4 + j)) << 10) + wcol);

  for (int tt = 0; tt < Tc; ++tt) {
    // ---- 3-pass compensated matvec, 6 interleaved accumulators ----
    float4v a1a = {}, a1b = {}, a2a = {}, a2b = {}, a3a = {}, a3b = {};
#pragma unroll
    for (int kk = 0; kk < 32; ++kk) {
      int ab = (((cn << 11) + kk * 64 + kg * 16) ^ ((cn & 7) << 4));
      half8 ah = *reinterpret_cast<const half8*>(reinterpret_cast<const char*>(Ahi) + ab);
      half8 al = *reinterpret_cast<const half8*>(reinterpret_cast<const char*>(Alo) + ab);
      if (kk & 1) {
        a1b = __builtin_amdgcn_mfma_f32_16x16x32_f16(ah, whi[kk], a1b, 0, 0, 0);
        a2b = __builtin_amdgcn_mfma_f32_16x16x32_f16(al, whi[kk], a2b, 0, 0, 0);
        a3b = __builtin_amdgcn_mfma_f32_16x16x32_f16(ah, wlo[kk], a3b, 0, 0, 0);
      } else {
        a1a = __builtin_amdgcn_mfma_f32_16x16x32_f16(ah, whi[kk], a1a, 0, 0, 0);
        a2a = __builtin_amdgcn_mfma_f32_16x16x32_f16(al, whi[kk], a2a, 0, 0, 0);
        a3a = __builtin_amdgcn_mfma_f32_16x16x32_f16(ah, wlo[kk], a3a, 0, 0, 0);
      }
    }

    // ---- epilogue ----
    const int tglob = t0 + tt;
    unsigned int* hexW = ((tt + 1) & 1) ? hexA : hexB;
#pragma unroll
    for (int j = 0; j < 4; ++j) {
      int row = r0 + kg * 4 + j;
      float v = (a1a[j] + a1b[j]) +
                (a2a[j] + a2b[j] + a3a[j] + a3b[j]) * LOINV +
                bhv + (float)bits16(xiu[j]);
      float h = tanhf(v);
      if (tt < Tc - 1) {
        _Float16 hi = (_Float16)h;
        _Float16 lo = (_Float16)((h - (float)hi) * LOSCALE);
        unsigned int u = (unsigned int)f16bits(hi) | ((unsigned int)f16bits(lo) << 16);
        // device-coherent store, no cache maintenance
        asm volatile("global_store_dword %0, %1, off sc0 sc1"
                     :: "v"((unsigned long long)(hexW + (((size_t)row) << 10) + wcol)),
                        "v"(u) : "memory");
      }
      if (tglob == SEQT - 1) out[(((size_t)row) << 10) + wcol] = h;
      else if (tt == Tc - 1) hstate[(((size_t)row) << 10) + wcol] = h;
    }
    if (tt == Tc - 1) break;  // no barrier/exchange after final step of chunk

    // xi prefetch for step tt+1 (issued before the barrier; hides latency)
#pragma unroll
    for (int j = 0; j < 4; ++j)
      xiu[j] = *reinterpret_cast<const unsigned short*>(
          xi + (((size_t)((tt + 1) * 256 + r0 + kg * 4 + j)) << 10) + wcol);

    // ---- fence-free flag barrier ----
    // producer ordering: every wave drains its h stores to the LLC, then the
    // group-wide __syncthreads, then tid 0 publishes the monotone flag.
    asm volatile("s_waitcnt vmcnt(0)" ::: "memory");
    __syncthreads();
    const int target = tt + 1;
    if (tid == 0)
      asm volatile("global_store_dword %0, %1, off sc0 sc1"
                   :: "v"((unsigned long long)(bar + (gb * 16 + gc) * 32)),
                      "v"(target) : "memory");
    if (tid < 16) {
      const int* fp = bar + (gb * 16 + tid) * 32;
      for (;;) {
        int v;
        asm volatile("global_load_dword %0, %1, off sc0 sc1\n\t"
                     "s_waitcnt vmcnt(0)"
                     : "=v"(v) : "v"((unsigned long long)fp) : "memory");
        if (v >= target) break;
        __builtin_amdgcn_s_sleep(1);
      }
    }
    __syncthreads();

    // ---- exchange: device-coherent load of full 16x1024 h, unpack to LDS ----
    const unsigned int* src = ((tt + 1) & 1) ? hexA : hexB;
    uint4v ta[8], tb[8];
#pragma unroll
    for (int p = 0; p < 8; ++p) {
      int idx = p * 256 + tid, row = idx >> 7, cc = idx & 127;
      unsigned long long ap =
          (unsigned long long)(src + (((size_t)(r0 + row)) << 10) + cc * 8);
      asm volatile("global_load_dwordx4 %0, %1, off sc0 sc1"
                   : "=v"(ta[p]) : "v"(ap) : "memory");
      asm volatile("global_load_dwordx4 %0, %1, off sc0 sc1"
                   : "=v"(tb[p]) : "v"(ap + 16) : "memory");
    }
    asm volatile("s_waitcnt vmcnt(0)" ::: "memory");
    __builtin_amdgcn_sched_barrier(0);
#pragma unroll
    for (int p = 0; p < 8; ++p) {
      int idx = p * 256 + tid, row = idx >> 7, cc = idx & 127;
      half8 vh, vl;
#pragma unroll
      for (int e = 0; e < 8; ++e) {
        unsigned int u = (e < 4) ? ta[p][e] : tb[p][e - 4];
        vh[e] = bits16((unsigned short)(u & 0xffffu));
        vl[e] = bits16((unsigned short)(u >> 16));
      }
      int bo = (((row << 11) + cc * 16) ^ ((row & 7) << 4));
      *reinterpret_cast<half8*>(reinterpret_cast<char*>(Ahi) + bo) = vh;
      *reinterpret_cast<half8*>(reinterpret_cast<char*>(Alo) + bo) = vl;
    }
    __syncthreads();
  }
}

extern "C" void kernel_launch(void* const* d_in, const int* in_sizes, int n_in,
                              void* d_out, int out_size, void* d_ws, size_t ws_size,
                              hipStream_t stream) {
  const int*   x   = (const int*)  d_in[0];
  const float* emb = (const float*)d_in[1];
  const float* Wi  = (const float*)d_in[2];
  const float* bi  = (const float*)d_in[3];
  const float* Wh  = (const float*)d_in[4];
  const float* bh  = (const float*)d_in[5];
  float* out = (float*)d_out;

  char* ws = (char*)d_ws;
  size_t off = 0;
  auto alloc = [&](size_t bytes) -> void* {
    void* p = ws + off;
    off = (off + bytes + 255) & ~(size_t)255;
    return p;
  };

  _Float16* embh   = (_Float16*)alloc((size_t)VOCABN * EMBED * 2);
  _Float16* Wih    = (_Float16*)alloc((size_t)HID * EMBED * 2);
  _Float16* Whih   = (_Float16*)alloc((size_t)HID * HID * 2);
  _Float16* Wloh   = (_Float16*)alloc((size_t)HID * HID * 2);
  float*    hstate = (float*)   alloc((size_t)BATCHN * HID * 4);
  unsigned int* hexA = (unsigned int*)alloc((size_t)BATCHN * HID * 4);
  unsigned int* hexB = (unsigned int*)alloc((size_t)BATCHN * HID * 4);
  int* bar  = (int*)alloc(256 * 32 * 4);   // 128B flag line per WG
  size_t fixed = off;

  // largest power-of-two T-chunk whose xi buffer fits in remaining ws
  int Tc = 1024;
  while (Tc > 4 && fixed + (size_t)BATCHN * Tc * HID * 2 > ws_size) Tc >>= 1;
  _Float16* xih = (_Float16*)alloc((size_t)BATCHN * Tc * HID * 2);

  {
    int n = VOCABN * EMBED;
    convert_f32_f16<<<n / 1024, 256, 0, stream>>>(emb, embh, n);
    n = HID * EMBED;
    convert_f32_f16<<<n / 1024, 256, 0, stream>>>(Wi, Wih, n);
    n = HID * HID;
    split_f32_f16<<<n / 1024, 256, 0, stream>>>(Wh, Whih, Wloh, n);
  }

  for (int t0 = 0; t0 < SEQT; t0 += Tc) {
    int grid = (BATCHN * Tc / 128) * 8;  // 128x128 tiles over [256*Tc, 1024]
    gemm_xi<<<grid, 256, 0, stream>>>(embh, Wih, x, bi, xih, t0, Tc);
    hipMemsetAsync(bar, 0, 256 * 32 * 4, stream);
    rnn_scan<<<256, 256, 0, stream>>>(Whih, Wloh, bh, xih, hstate, out,
                                      hexA, hexB, bar, t0, Tc);
  }
}